// Round 5
// baseline (1083.571 us; speedup 1.0000x reference)
//
#include <hip/hip_runtime.h>
#include <stdint.h>

typedef unsigned short u16;
typedef __attribute__((ext_vector_type(4))) float f32x4;
typedef __attribute__((ext_vector_type(8))) __bf16 bf16x8;
typedef __attribute__((ext_vector_type(8))) unsigned short u16x8;

__device__ __forceinline__ u16 f2bf(float f) {
  unsigned u = __builtin_bit_cast(unsigned, f);
  u = (u + 0x7fffu + ((u >> 16) & 1u)) >> 16;
  return (u16)u;
}

typedef __attribute__((address_space(1))) const void gvoid_t;
typedef __attribute__((address_space(3))) void lvoid_t;

__device__ __forceinline__ void gload_lds16(const void* g, void* l) {
  __builtin_amdgcn_global_load_lds((gvoid_t*)g, (lvoid_t*)l, 16, 0, 0);
}

// ---------------- dequant: w[row][k] = (q[row][k] - z[row][k/128]) * s[row][k/128], bf16
__global__ __launch_bounds__(256)
void dequant_kernel(const int* __restrict__ q, const float* __restrict__ s,
                    const int* __restrict__ z, u16* __restrict__ w, int K) {
  const int row = blockIdx.y;
  const int k = (blockIdx.x * 256 + threadIdx.x) << 3;
  const int ng = K >> 7;
  const int g = k >> 7;
  const float sv = s[(size_t)row * ng + g];
  const float zv = (float)z[(size_t)row * ng + g];
  const int4* qp = (const int4*)(q + (size_t)row * K + k);
  const int4 a = qp[0], b = qp[1];
  u16x8 o;
  o[0] = f2bf(((float)a.x - zv) * sv);
  o[1] = f2bf(((float)a.y - zv) * sv);
  o[2] = f2bf(((float)a.z - zv) * sv);
  o[3] = f2bf(((float)a.w - zv) * sv);
  o[4] = f2bf(((float)b.x - zv) * sv);
  o[5] = f2bf(((float)b.y - zv) * sv);
  o[6] = f2bf(((float)b.z - zv) * sv);
  o[7] = f2bf(((float)b.w - zv) * sv);
  *reinterpret_cast<u16x8*>(w + (size_t)row * K + k) = o;
}

// ---------------- fp32 -> bf16 bulk convert (x)
__global__ __launch_bounds__(256)
void cvt_kernel(const float* __restrict__ in, u16* __restrict__ out) {
  const size_t i = ((size_t)blockIdx.x * 256 + threadIdx.x) << 3;
  const float4* p = (const float4*)(in + i);
  const float4 a = p[0], b = p[1];
  u16x8 o;
  o[0] = f2bf(a.x); o[1] = f2bf(a.y); o[2] = f2bf(a.z); o[3] = f2bf(a.w);
  o[4] = f2bf(b.x); o[5] = f2bf(b.y); o[6] = f2bf(b.z); o[7] = f2bf(b.w);
  *reinterpret_cast<u16x8*>(out + i) = o;
}

// ---------------- 256x256 8-phase GEMM v3 (m201-faithful gates): C = A * B^T (bf16, K-major)
// 512 thr = 8 waves (2M x 4N); per-wave 128x64; BK=64; buf parity = K-tile parity.
// Region ledger (per iteration, tiles T0=2it in buf0 / T1=2it+1 in buf1):
//   reads: ph1 a1(af0-3 ks0)+b1(bfr ks0); ph2 a2,a4,a3 (rest of A; buf.A free);
//          ph3 b2 (bfr ks1; buf.B free); ph4 none. Per-phase lgkmcnt(0) makes
//          "free" sound at that phase's trailing barrier.
//   MFMA:  ph1 a1*b1->acc[0-3]; ph2 a2*b1->acc[4-7]; ph3 a4*b2->acc[4-7]; ph4 a3*b2->acc[0-3].
//   stages (1 half-tile = 2 gload/phase): ph1-2 B(T1)->buf1.B; ph3-4 A(T0+2)->buf0.A;
//          ph5-6 B(T0+2)->buf0.B; ph7-8 A(T1+2)->buf1.A.
//   gates: vmcnt(4) at ph4 (12 outstanding -> leaves ph3-4's A(T0+2); B(T1)+prev A(T1) landed)
//          and ph8 (leaves ph7-8's A(T1+2); A/B(T0+2) landed). NEVER vmcnt(0) in loop (T4).
template<bool RELU2>
__global__ __launch_bounds__(512, 2)
void gemm256(const u16* __restrict__ Ap, const u16* __restrict__ Bp,
             void* __restrict__ Cptr, int M, int N, int K) {
  __shared__ __align__(16) u16 As[2][256][64];
  __shared__ __align__(16) u16 Bs[2][256][64];
  const int tid = threadIdx.x;
  const int lane = tid & 63;
  const int wid = tid >> 6;
  const int wr = wid >> 2, wc = wid & 3;

  const int nbx = N >> 8;
  const int nwg = gridDim.x;
  int bid = blockIdx.x;
  bid = (bid & 7) * (nwg >> 3) + (bid >> 3);   // XCD swizzle (nwg % 8 == 0)
  const int m0 = (bid / nbx) << 8;
  const int n0 = (bid % nbx) << 8;

  const int srow = tid >> 3;        // staging row within 64-row sweep
  const int scol = tid & 7;         // staging 16B segment
  const int lr = lane & 15;
  const int lk = (lane >> 4) << 3;
  const int xorc = (lr & 7) << 3;   // read-side swizzle (row&7 == lr&7)

  f32x4 acc[8][4] = {};
  bf16x8 a1[4], a2[4], a3[4], a4[4], b1[4], b2[4];

  const int nk = K >> 6;

#define STG_A(bufi, h, kt) do { _Pragma("unroll") \
  for (int l_ = 0; l_ < 2; ++l_) { \
    const int r_ = (h) * 128 + l_ * 64 + srow; \
    gload_lds16(Ap + (size_t)(m0 + r_) * K + (size_t)((kt) << 6) + ((scol ^ (srow & 7)) << 3), \
                &As[bufi][r_][scol << 3]); } } while (0)
#define STG_B(bufi, h, kt) do { _Pragma("unroll") \
  for (int l_ = 0; l_ < 2; ++l_) { \
    const int r_ = (h) * 128 + l_ * 64 + srow; \
    gload_lds16(Bp + (size_t)(n0 + r_) * K + (size_t)((kt) << 6) + ((scol ^ (srow & 7)) << 3), \
                &Bs[bufi][r_][scol << 3]); } } while (0)
#define RD_A(bufi, ks, half, dst) do { _Pragma("unroll") \
  for (int i_ = 0; i_ < 4; ++i_) { \
    const int row_ = wr * 128 + ((half) * 4 + i_) * 16 + lr; \
    dst[i_] = *reinterpret_cast<const bf16x8*>(&As[bufi][row_][((ks) * 32 + lk) ^ xorc]); } } while (0)
#define RD_B(bufi, ks, dst) do { _Pragma("unroll") \
  for (int j_ = 0; j_ < 4; ++j_) { \
    const int row_ = wc * 64 + j_ * 16 + lr; \
    dst[j_] = *reinterpret_cast<const bf16x8*>(&Bs[bufi][row_][((ks) * 32 + lk) ^ xorc]); } } while (0)
#define MFMA16(ASET, BSET, I0) do { _Pragma("unroll") \
  for (int i_ = 0; i_ < 4; ++i_) { _Pragma("unroll") \
    for (int j_ = 0; j_ < 4; ++j_) \
      acc[(I0) + i_][j_] = __builtin_amdgcn_mfma_f32_16x16x32_bf16( \
        ASET[i_], BSET[j_], acc[(I0) + i_][j_], 0, 0, 0); } } while (0)
#define BAR() do { asm volatile("" ::: "memory"); __builtin_amdgcn_s_barrier(); \
  asm volatile("" ::: "memory"); } while (0)
// phase tail: BAR, full lgkm drain (region-ledger soundness), sched fence (rule #18),
// prioritized MFMA cluster, optional counted-vmcnt gate, BAR.
#define PH(Q) do { BAR(); \
  asm volatile("s_waitcnt lgkmcnt(0)" ::: "memory"); \
  __builtin_amdgcn_sched_barrier(0); \
  __builtin_amdgcn_s_setprio(1); Q; __builtin_amdgcn_s_setprio(0); \
  BAR(); } while (0)
#define PH_GATE(Q) do { BAR(); \
  asm volatile("s_waitcnt lgkmcnt(0)" ::: "memory"); \
  __builtin_amdgcn_sched_barrier(0); \
  __builtin_amdgcn_s_setprio(1); Q; __builtin_amdgcn_s_setprio(0); \
  asm volatile("s_waitcnt vmcnt(4)" ::: "memory"); \
  BAR(); } while (0)
// 4 phases of one K-tile in buf p; S1..S4 = one half-tile stage each; ph4 gated.
#define TILE4(p, S1, S2, S3, S4) do { \
  RD_A(p, 0, 0, a1); RD_B(p, 0, b1); S1; PH(MFMA16(a1, b1, 0)); \
  RD_A(p, 0, 1, a2); RD_A(p, 1, 1, a4); RD_A(p, 1, 0, a3); S2; PH(MFMA16(a2, b1, 4)); \
  RD_B(p, 1, b2); S3; PH(MFMA16(a4, b2, 4)); \
  S4; PH_GATE(MFMA16(a3, b2, 0)); } while (0)

  // prologue: A(0),B(0)->buf0, A(1)->buf1 (6 half-tiles); gate leaves A(1) in flight
  STG_A(0, 0, 0); STG_A(0, 1, 0);
  STG_B(0, 0, 0); STG_B(0, 1, 0);
  STG_A(1, 0, 1); STG_A(1, 1, 1);
  asm volatile("s_waitcnt vmcnt(4)" ::: "memory");
  BAR();

  const int nit = nk >> 1;
  for (int it = 0; it < nit; ++it) {
    const int t1 = 2 * it + 1;
    int t2 = 2 * it + 2; if (t2 >= nk) t2 -= nk;   // wrap: tail stages are dummies
    int t3 = 2 * it + 3; if (t3 >= nk) t3 -= nk;
    TILE4(0, STG_B(1, 0, t1), STG_B(1, 1, t1), STG_A(0, 0, t2), STG_A(0, 1, t2));
    TILE4(1, STG_B(0, 0, t2), STG_B(0, 1, t2), STG_A(1, 0, t3), STG_A(1, 1, t3));
  }
  asm volatile("s_waitcnt vmcnt(0)" ::: "memory");  // drain dummy stages before epilogue

  // epilogue: C/D layout col = lane&15, row = (lane>>4)*4 + reg  [m89-verified]
  const int crow = (lane >> 4) << 2;
  const int ccol = lane & 15;
#pragma unroll
  for (int i = 0; i < 8; ++i) {
#pragma unroll
    for (int j = 0; j < 4; ++j) {
#pragma unroll
      for (int q = 0; q < 4; ++q) {
        const int m = m0 + wr * 128 + i * 16 + crow + q;
        const int n = n0 + wc * 64 + j * 16 + ccol;
        const float v = acc[i][j][q];
        if constexpr (RELU2) {
          const float r = fmaxf(v, 0.f);
          ((u16*)Cptr)[(size_t)m * N + n] = f2bf(r * r);
        } else {
          ((float*)Cptr)[(size_t)m * N + n] = v;
        }
      }
    }
  }
#undef STG_A
#undef STG_B
#undef RD_A
#undef RD_B
#undef MFMA16
#undef BAR
#undef PH
#undef PH_GATE
#undef TILE4
}

extern "C" void kernel_launch(void* const* d_in, const int* in_sizes, int n_in,
                              void* d_out, int out_size, void* d_ws, size_t ws_size,
                              hipStream_t stream) {
  const float* x    = (const float*)d_in[0];
  const int*   q_up = (const int*)d_in[1];
  const float* s_up = (const float*)d_in[2];
  const int*   z_up = (const int*)d_in[3];
  const int*   q_dn = (const int*)d_in[4];
  const float* s_dn = (const float*)d_in[5];
  const int*   z_dn = (const int*)d_in[6];
  float* y = (float*)d_out;

  const int H = 4096, I = 14336;
  const int M = in_sizes[0] / H;  // 4096 tokens

  const size_t wbytes = (size_t)I * H * 2;   // 117.4 MB bf16 weight buffer (reused)
  const size_t abytes = (size_t)M * I * 2;   // 117.4 MB bf16 activations
  const size_t xbytes = (size_t)M * H * 2;   // 33.5 MB bf16 x
  u16* wbuf = (u16*)d_ws;
  u16* abuf = (u16*)((char*)d_ws + wbytes);
  u16* xbf  = (u16*)((char*)d_ws + wbytes + abytes);
  if (ws_size < wbytes + abytes + xbytes) return;  // insufficient scratch: fail cleanly

  // 1. dequant W_up [I, H] -> bf16
  dequant_kernel<<<dim3(H / 8 / 256, I), 256, 0, stream>>>(q_up, s_up, z_up, wbuf, H);
  // 1b. x -> bf16
  cvt_kernel<<<dim3((int)(((size_t)M * H) >> 11)), 256, 0, stream>>>(x, xbf);
  // 2. a = relu(x @ W_up^T)^2, bf16   (grid 896 % 8 == 0)
  gemm256<true><<<dim3((M / 256) * (I / 256)), 512, 0, stream>>>(xbf, wbuf, abuf, M, I, H);
  // 3. dequant W_down [H, I] -> bf16
  dequant_kernel<<<dim3(I / 8 / 256, H), 256, 0, stream>>>(q_dn, s_dn, z_dn, wbuf, I);
  // 4. y = a @ W_down^T, fp32   (grid 256 % 8 == 0)
  gemm256<false><<<dim3((M / 256) * (H / 256)), 512, 0, stream>>>(abuf, wbuf, y, M, H, I);
}

// Round 6
// 1046.965 us; speedup vs baseline: 1.0350x; 1.0350x over previous
//
#include <hip/hip_runtime.h>
#include <stdint.h>

typedef unsigned short u16;
typedef __attribute__((ext_vector_type(4))) float f32x4;
typedef __attribute__((ext_vector_type(8))) __bf16 bf16x8;
typedef __attribute__((ext_vector_type(8))) unsigned short u16x8;

__device__ __forceinline__ u16 f2bf(float f) {
  unsigned u = __builtin_bit_cast(unsigned, f);
  u = (u + 0x7fffu + ((u >> 16) & 1u)) >> 16;
  return (u16)u;
}

typedef __attribute__((address_space(1))) const void gvoid_t;
typedef __attribute__((address_space(3))) void lvoid_t;

__device__ __forceinline__ void gload_lds16(const void* g, void* l) {
  __builtin_amdgcn_global_load_lds((gvoid_t*)g, (lvoid_t*)l, 16, 0, 0);
}

// ---------------- dequant: w[row][k] = (q[row][k] - z[row][k/128]) * s[row][k/128], bf16
__global__ __launch_bounds__(256)
void dequant_kernel(const int* __restrict__ q, const float* __restrict__ s,
                    const int* __restrict__ z, u16* __restrict__ w, int K) {
  const int row = blockIdx.y;
  const int k = (blockIdx.x * 256 + threadIdx.x) << 3;
  const int ng = K >> 7;
  const int g = k >> 7;
  const float sv = s[(size_t)row * ng + g];
  const float zv = (float)z[(size_t)row * ng + g];
  const int4* qp = (const int4*)(q + (size_t)row * K + k);
  const int4 a = qp[0], b = qp[1];
  u16x8 o;
  o[0] = f2bf(((float)a.x - zv) * sv);
  o[1] = f2bf(((float)a.y - zv) * sv);
  o[2] = f2bf(((float)a.z - zv) * sv);
  o[3] = f2bf(((float)a.w - zv) * sv);
  o[4] = f2bf(((float)b.x - zv) * sv);
  o[5] = f2bf(((float)b.y - zv) * sv);
  o[6] = f2bf(((float)b.z - zv) * sv);
  o[7] = f2bf(((float)b.w - zv) * sv);
  *reinterpret_cast<u16x8*>(w + (size_t)row * K + k) = o;
}

// ---------------- fp32 -> bf16 bulk convert (x)
__global__ __launch_bounds__(256)
void cvt_kernel(const float* __restrict__ in, u16* __restrict__ out) {
  const size_t i = ((size_t)blockIdx.x * 256 + threadIdx.x) << 3;
  const float4* p = (const float4*)(in + i);
  const float4 a = p[0], b = p[1];
  u16x8 o;
  o[0] = f2bf(a.x); o[1] = f2bf(a.y); o[2] = f2bf(a.z); o[3] = f2bf(a.w);
  o[4] = f2bf(b.x); o[5] = f2bf(b.y); o[6] = f2bf(b.z); o[7] = f2bf(b.w);
  *reinterpret_cast<u16x8*>(out + i) = o;
}

// ---------------- 256x256 8-phase GEMM v4 (1 barrier/phase): C = A * B^T (bf16, K-major)
// 512 thr = 8 waves (2M x 4N); per-wave 128x64; BK=64; buf parity = K-tile parity.
// Phase = { RD_i; STG_i; lgkmcnt(0); sched_barrier; [vmcnt gate]; BAR; setprio+MFMA_i }.
// Reads complete BEFORE the barrier (stage-after-read sound with ONE barrier);
// MFMA_i sits between BAR_i and RD_{i+1} with no barrier between -> compiler
// interleaves next reads under the MFMA cluster (LDS never idles during MFMA).
// Ledger (iter: T0=2it buf0, T1 buf1; per-thread loads: 2/STG):
//  ph1 rd a1,b1   stg B(T1)h0   ph2 rd a2,a4,a3 stg B(T1)h1   (buf0.A free @BAR2)
//  ph3 rd b2      stg A(T2)h0   (buf0.B free @BAR3)           ph4 stg A(T2)h1, GATE
//  ph5-8 mirror buf1: stg B(T2)h0/h1, A(T3)h0/h1, GATE @ph8.
//  GATE = vmcnt(4): ph4 has 12 outstanding {A(T1)4,B(T1)4,A(T2)4} -> completes
//  A(T1)+B(T1) (needed by ph5+) leaving A(T2); ph8 completes A(T2)+B(T2)
//  (needed by next ph1) leaving A(T3). In-order completion guarantees exactness.
template<bool RELU2>
__global__ __launch_bounds__(512, 2)
void gemm256(const u16* __restrict__ Ap, const u16* __restrict__ Bp,
             void* __restrict__ Cptr, int M, int N, int K) {
  __shared__ __align__(16) u16 As[2][256][64];
  __shared__ __align__(16) u16 Bs[2][256][64];
  const int tid = threadIdx.x;
  const int lane = tid & 63;
  const int wid = tid >> 6;
  const int wr = wid >> 2, wc = wid & 3;

  const int nbx = N >> 8;
  const int nwg = gridDim.x;
  int bid = blockIdx.x;
  bid = (bid & 7) * (nwg >> 3) + (bid >> 3);   // XCD swizzle (nwg % 8 == 0)
  const int m0 = (bid / nbx) << 8;
  const int n0 = (bid % nbx) << 8;

  const int srow = tid >> 3;        // staging row within 64-row sweep
  const int scol = tid & 7;         // staging 16B segment
  const int lr = lane & 15;
  const int lk = (lane >> 4) << 3;
  const int xorc = (lr & 7) << 3;   // read-side swizzle (row&7 == lr&7)

  f32x4 acc[8][4] = {};
  bf16x8 a1[4], a2[4], a3[4], a4[4], b1[4], b2[4];

  const int nk = K >> 6;

#define STG_A(bufi, h, kt) do { _Pragma("unroll") \
  for (int l_ = 0; l_ < 2; ++l_) { \
    const int r_ = (h) * 128 + l_ * 64 + srow; \
    gload_lds16(Ap + (size_t)(m0 + r_) * K + (size_t)((kt) << 6) + ((scol ^ (srow & 7)) << 3), \
                &As[bufi][r_][scol << 3]); } } while (0)
#define STG_B(bufi, h, kt) do { _Pragma("unroll") \
  for (int l_ = 0; l_ < 2; ++l_) { \
    const int r_ = (h) * 128 + l_ * 64 + srow; \
    gload_lds16(Bp + (size_t)(n0 + r_) * K + (size_t)((kt) << 6) + ((scol ^ (srow & 7)) << 3), \
                &Bs[bufi][r_][scol << 3]); } } while (0)
#define RD_A(bufi, ks, half, dst) do { _Pragma("unroll") \
  for (int i_ = 0; i_ < 4; ++i_) { \
    const int row_ = wr * 128 + ((half) * 4 + i_) * 16 + lr; \
    dst[i_] = *reinterpret_cast<const bf16x8*>(&As[bufi][row_][((ks) * 32 + lk) ^ xorc]); } } while (0)
#define RD_B(bufi, ks, dst) do { _Pragma("unroll") \
  for (int j_ = 0; j_ < 4; ++j_) { \
    const int row_ = wc * 64 + j_ * 16 + lr; \
    dst[j_] = *reinterpret_cast<const bf16x8*>(&Bs[bufi][row_][((ks) * 32 + lk) ^ xorc]); } } while (0)
#define MFMA16(ASET, BSET, I0) do { _Pragma("unroll") \
  for (int i_ = 0; i_ < 4; ++i_) { _Pragma("unroll") \
    for (int j_ = 0; j_ < 4; ++j_) \
      acc[(I0) + i_][j_] = __builtin_amdgcn_mfma_f32_16x16x32_bf16( \
        ASET[i_], BSET[j_], acc[(I0) + i_][j_], 0, 0, 0); } } while (0)
// phase: reads done pre-barrier; MFMA post-barrier, open-ended (next phase's
// reads/stages may interleave under it — that is the point).
#define PH(GATEOP, Q) do { \
  asm volatile("s_waitcnt lgkmcnt(0)" ::: "memory"); \
  __builtin_amdgcn_sched_barrier(0); \
  GATEOP; \
  asm volatile("" ::: "memory"); __builtin_amdgcn_s_barrier(); \
  asm volatile("" ::: "memory"); \
  __builtin_amdgcn_s_setprio(1); Q; __builtin_amdgcn_s_setprio(0); \
} while (0)
#define NOGATE do {} while (0)
#define GATE4 asm volatile("s_waitcnt vmcnt(4)" ::: "memory")
// 4 phases of one K-tile in buf p; S1..S4 = one half-tile stage (2 loads) each.
#define TILE4(p, S1, S2, S3, S4) do { \
  RD_A(p, 0, 0, a1); RD_B(p, 0, b1); S1; PH(NOGATE, MFMA16(a1, b1, 0)); \
  RD_A(p, 0, 1, a2); RD_A(p, 1, 1, a4); RD_A(p, 1, 0, a3); S2; PH(NOGATE, MFMA16(a2, b1, 4)); \
  RD_B(p, 1, b2); S3; PH(NOGATE, MFMA16(a4, b2, 4)); \
  S4; PH(GATE4, MFMA16(a3, b2, 0)); } while (0)

  // prologue: A(0),B(0)->buf0, A(1)->buf1 (12 loads); gate leaves A(1) in flight
  STG_A(0, 0, 0); STG_A(0, 1, 0);
  STG_B(0, 0, 0); STG_B(0, 1, 0);
  STG_A(1, 0, 1); STG_A(1, 1, 1);
  asm volatile("s_waitcnt vmcnt(4)" ::: "memory");
  asm volatile("" ::: "memory"); __builtin_amdgcn_s_barrier();
  asm volatile("" ::: "memory");

  const int nit = nk >> 1;
  for (int it = 0; it < nit; ++it) {
    const int t1 = 2 * it + 1;
    int t2 = 2 * it + 2; if (t2 >= nk) t2 -= nk;   // wrap: tail stages are dummies
    int t3 = 2 * it + 3; if (t3 >= nk) t3 -= nk;
    TILE4(0, STG_B(1, 0, t1), STG_B(1, 1, t1), STG_A(0, 0, t2), STG_A(0, 1, t2));
    TILE4(1, STG_B(0, 0, t2), STG_B(0, 1, t2), STG_A(1, 0, t3), STG_A(1, 1, t3));
  }
  asm volatile("s_waitcnt vmcnt(0)" ::: "memory");  // drain dummy stages before epilogue

  // epilogue: C/D layout col = lane&15, row = (lane>>4)*4 + reg  [m89-verified]
  const int crow = (lane >> 4) << 2;
  const int ccol = lane & 15;
#pragma unroll
  for (int i = 0; i < 8; ++i) {
#pragma unroll
    for (int j = 0; j < 4; ++j) {
#pragma unroll
      for (int q = 0; q < 4; ++q) {
        const int m = m0 + wr * 128 + i * 16 + crow + q;
        const int n = n0 + wc * 64 + j * 16 + ccol;
        const float v = acc[i][j][q];
        if constexpr (RELU2) {
          const float r = fmaxf(v, 0.f);
          ((u16*)Cptr)[(size_t)m * N + n] = f2bf(r * r);
        } else {
          ((float*)Cptr)[(size_t)m * N + n] = v;
        }
      }
    }
  }
#undef STG_A
#undef STG_B
#undef RD_A
#undef RD_B
#undef MFMA16
#undef PH
#undef NOGATE
#undef GATE4
#undef TILE4
}

extern "C" void kernel_launch(void* const* d_in, const int* in_sizes, int n_in,
                              void* d_out, int out_size, void* d_ws, size_t ws_size,
                              hipStream_t stream) {
  const float* x    = (const float*)d_in[0];
  const int*   q_up = (const int*)d_in[1];
  const float* s_up = (const float*)d_in[2];
  const int*   z_up = (const int*)d_in[3];
  const int*   q_dn = (const int*)d_in[4];
  const float* s_dn = (const float*)d_in[5];
  const int*   z_dn = (const int*)d_in[6];
  float* y = (float*)d_out;

  const int H = 4096, I = 14336;
  const int M = in_sizes[0] / H;  // 4096 tokens

  const size_t wbytes = (size_t)I * H * 2;   // 117.4 MB bf16 weight buffer (reused)
  const size_t abytes = (size_t)M * I * 2;   // 117.4 MB bf16 activations
  const size_t xbytes = (size_t)M * H * 2;   // 33.5 MB bf16 x
  u16* wbuf = (u16*)d_ws;
  u16* abuf = (u16*)((char*)d_ws + wbytes);
  u16* xbf  = (u16*)((char*)d_ws + wbytes + abytes);
  if (ws_size < wbytes + abytes + xbytes) return;  // insufficient scratch: fail cleanly

  // 1. dequant W_up [I, H] -> bf16
  dequant_kernel<<<dim3(H / 8 / 256, I), 256, 0, stream>>>(q_up, s_up, z_up, wbuf, H);
  // 1b. x -> bf16
  cvt_kernel<<<dim3((int)(((size_t)M * H) >> 11)), 256, 0, stream>>>(x, xbf);
  // 2. a = relu(x @ W_up^T)^2, bf16   (grid 896 % 8 == 0)
  gemm256<true><<<dim3((M / 256) * (I / 256)), 512, 0, stream>>>(xbf, wbuf, abuf, M, I, H);
  // 3. dequant W_down [H, I] -> bf16
  dequant_kernel<<<dim3(I / 8 / 256, H), 256, 0, stream>>>(q_dn, s_dn, z_dn, wbuf, I);
  // 4. y = a @ W_down^T, fp32   (grid 256 % 8 == 0)
  gemm256<false><<<dim3((M / 256) * (H / 256)), 512, 0, stream>>>(abuf, wbuf, y, M, H, I);
}